// Round 14
// baseline (32.204 us; speedup 1.0000x reference)
//
#include <hip/hip_runtime.h>

#define NODES 14
#define IN_F 24
#define HID1 32
#define HID2 64
#define OUT_F 24
#define SLOPE 0.2f

#define H1_S 36   // h1 stride (float4-aligned)
#define H2_S 68   // h2 stride (float4-aligned)

// u-vector layout in d_ws: us1[48] ud1[48] us2[64] ud2[64]  (224 floats)
#define U_US1 0
#define U_UD1 48
#define U_US2 96
#define U_UD2 160

#define PHASE_FENCE() __builtin_amdgcn_sched_barrier(0)

// ---- kernel 1: precompute u = W @ a  (graph-invariant, once) ----
__global__ __launch_bounds__(256) void compute_uvecs(
    const float* __restrict__ W1, const float* __restrict__ a_src1,
    const float* __restrict__ a_dst1,
    const float* __restrict__ W2, const float* __restrict__ a_src2,
    const float* __restrict__ a_dst2, float* __restrict__ u)
{
  const int tid = threadIdx.x;
  if (tid < 96) {
    const int sd = (tid >= 48), r = tid - sd * 48;
    const int h = (r >= IN_F), k = r - h * IN_F;
    const float* av = sd ? a_dst1 : a_src1;
    float s = 0.f;
#pragma unroll
    for (int f = 0; f < HID1; ++f)
      s += W1[k * 64 + h * HID1 + f] * av[h * HID1 + f];
    u[(sd ? U_UD1 : U_US1) + h * IN_F + k] = s;
  } else if (tid < 224) {
    const int j = tid - 96;
    const int sd = (j >= 64), r = j - sd * 64;
    const int h = (r >= HID1), k = r - h * HID1;
    const float* av = sd ? a_dst2 : a_src2;
    float s = 0.f;
#pragma unroll
    for (int f = 0; f < HID2; ++f)
      s += W2[k * 128 + h * HID2 + f] * av[h * HID2 + f];
    u[(sd ? U_UD2 : U_US2) + h * HID1 + k] = s;
  }
}

// ---- kernel 2: fused GNN+MLP, one graph per 128-thread block ----
// R14: head-parallel waves. Wave w owns GAT head w end-to-end (heads are
// independent until the head-mean): GEMM1 k-split+shfl, logits/softmax
// per-wave (head w only), agg with bias pre-folded (write o+b so the
// cross-head mean 0.5(A+B) lands at 0.5*sum+b). Cross-wave contact is
// only the two mean-combines and the MLP handoff -> 4 barriers, zero
// wave-specialization idling, ELU computed once per element.
__global__ __launch_bounds__(128) void gnn_fused(
    const float* __restrict__ x, const float* __restrict__ y,
    const float* __restrict__ W1, const float* __restrict__ b1,
    const float* __restrict__ W2, const float* __restrict__ b2,
    const float* __restrict__ Wf1, const float* __restrict__ bf1,
    const float* __restrict__ Wf2, const float* __restrict__ bf2,
    const float* __restrict__ uvec,
    float* __restrict__ out, int ngraphs)
{
  const int g = blockIdx.x;
  const int tid = threadIdx.x;
  const int lane = tid & 63;
  const int w = tid >> 6;          // wave = head
  const int l5 = lane & 31;
  const int kh = lane >> 5;        // k-half for GEMM1 / node-half for agg1

  __shared__ __align__(16) float h1p[2][NODES * H1_S];  // per-head agg1 out
  __shared__ __align__(16) float h1s[NODES * H1_S];     // combined h1
  __shared__ __align__(16) float wt1[2][NODES * 16];    // [head][dst][src]
  __shared__ __align__(16) float wt2[2][NODES * 16];
  __shared__ __align__(16) float als2[2][16], ald2[2][16];
  __shared__ __align__(16) float h2p[2][NODES * H2_S];  // per-head agg2 out
  __shared__ __align__(16) float hhs[112];

  const float* xg = x + (size_t)g * (NODES * IN_F);

  // ---- P0: y-copy (independent) ----
  if (tid < (NODES * OUT_F) / 4) {
    const float4* y4 = (const float4*)(y + (size_t)g * (NODES * OUT_F));
    float4* o4 = (float4*)(out + (size_t)NODES * ngraphs * OUT_F
                               + (size_t)g * (NODES * OUT_F));
    o4[tid] = y4[tid];
  }

  // ---- P1a: GEMM1 — col = 32w+l5 (head w), k-half kh, combine via shfl ----
  float xcol[NODES];
  {
    const int col = 32 * w + l5;
    float w1r[12];
#pragma unroll
    for (int k = 0; k < 12; ++k) w1r[k] = W1[(kh * 12 + k) * 64 + col];
#pragma unroll 2
    for (int n = 0; n < NODES; ++n) {
      float acc = 0.f;
#pragma unroll
      for (int k4 = 0; k4 < 3; ++k4) {
        const float4 xv = *(const float4*)&xg[n * IN_F + kh * 12 + k4 * 4];
        acc += xv.x * w1r[k4 * 4 + 0] + xv.y * w1r[k4 * 4 + 1]
             + xv.z * w1r[k4 * 4 + 2] + xv.w * w1r[k4 * 4 + 3];
      }
      xcol[n] = acc;
    }
#pragma unroll
    for (int n = 0; n < NODES; ++n) xcol[n] += __shfl_xor(xcol[n], 32);
  }
  PHASE_FENCE();

  // ---- P1b: logits1 — head w only (28 lanes/wave, global x & u) ----
  if (lane < 28) {
    const int n = lane >> 1, sd = lane & 1;
    const float* uu = uvec + (sd ? U_UD1 : U_US1) + w * IN_F;
    float s = 0.f;
#pragma unroll
    for (int k4 = 0; k4 < 6; ++k4) {
      const float4 xv = *(const float4*)&xg[n * IN_F + k4 * 4];
      const float4 uv = *(const float4*)&uu[k4 * 4];
      s += xv.x * uv.x + xv.y * uv.y + xv.z * uv.z + xv.w * uv.w;
    }
    (sd ? ald2 : als2)[w][n] = s;
  }
  // ---- P1c: softmax1 — head w (14 lanes/wave, wave-internal ordering) ----
  if (lane < NODES) {
    const float ad = ald2[w][lane];
    const float4 A0 = *(const float4*)&als2[w][0];
    const float4 A1 = *(const float4*)&als2[w][4];
    const float4 A2 = *(const float4*)&als2[w][8];
    const float2 A3 = *(const float2*)&als2[w][12];
    float a[NODES] = {A0.x, A0.y, A0.z, A0.w, A1.x, A1.y, A1.z, A1.w,
                      A2.x, A2.y, A2.z, A2.w, A3.x, A3.y};
    float m = -1e30f;
#pragma unroll
    for (int i = 0; i < NODES; ++i) {
      float v = a[i] + ad;
      v = v > 0.f ? v : SLOPE * v;
      a[i] = v; m = fmaxf(m, v);
    }
    float den = 0.f;
#pragma unroll
    for (int i = 0; i < NODES; ++i) { a[i] = __expf(a[i] - m); den += a[i]; }
    const float r = 1.f / den;
    float* wr = &wt1[w][lane * 16];
    *(float4*)&wr[0]  = make_float4(a[0]*r,  a[1]*r,  a[2]*r,  a[3]*r);
    *(float4*)&wr[4]  = make_float4(a[4]*r,  a[5]*r,  a[6]*r,  a[7]*r);
    *(float4*)&wr[8]  = make_float4(a[8]*r,  a[9]*r,  a[10]*r, a[11]*r);
    *(float2*)&wr[12] = make_float2(a[12]*r, a[13]*r);
  }
  // ---- P1d: agg1 — head w, node-half kh; bias pre-folded ----
  {
    const float bb = b1[l5];
#pragma unroll
    for (int t = 0; t < NODES / 2; ++t) {
      const int n = kh * (NODES / 2) + t;
      const float* wr = &wt1[w][n * 16];
      const float4 w0 = *(const float4*)&wr[0];
      const float4 w1 = *(const float4*)&wr[4];
      const float4 w2 = *(const float4*)&wr[8];
      const float2 w3 = *(const float2*)&wr[12];
      const float o = w0.x*xcol[0] + w0.y*xcol[1] + w0.z*xcol[2] + w0.w*xcol[3]
                    + w1.x*xcol[4] + w1.y*xcol[5] + w1.z*xcol[6] + w1.w*xcol[7]
                    + w2.x*xcol[8] + w2.y*xcol[9] + w2.z*xcol[10] + w2.w*xcol[11]
                    + w3.x*xcol[12] + w3.y*xcol[13];
      h1p[w][n * H1_S + l5] = o + bb;
    }
  }
  __syncthreads();              // B1: h1p ready
  PHASE_FENCE();

  // ---- P2: combine h1 = elu(0.5*(A+B)) — wave w does nodes [7w,7w+7) ----
  if (lane < 56) {
    const int n = 7 * w + (lane >> 3), f4 = (lane & 7) * 4;
    const float4 A = *(const float4*)&h1p[0][n * H1_S + f4];
    const float4 B = *(const float4*)&h1p[1][n * H1_S + f4];
    float4 v;
    v.x = 0.5f * (A.x + B.x); v.y = 0.5f * (A.y + B.y);
    v.z = 0.5f * (A.z + B.z); v.w = 0.5f * (A.w + B.w);
    v.x = v.x > 0.f ? v.x : expm1f(v.x);
    v.y = v.y > 0.f ? v.y : expm1f(v.y);
    v.z = v.z > 0.f ? v.z : expm1f(v.z);
    v.w = v.w > 0.f ? v.w : expm1f(v.w);
    *(float4*)&h1s[n * H1_S + f4] = v;
  }
  __syncthreads();              // B2: h1s ready
  PHASE_FENCE();

  // ---- P3a: GEMM2 — col = 64w+lane (head w) ----
  float x2c[NODES];
  {
    float w2r[HID1];
#pragma unroll
    for (int k = 0; k < HID1; ++k) w2r[k] = W2[k * 128 + 64 * w + lane];
#pragma unroll 2
    for (int n = 0; n < NODES; ++n) {
      float acc = 0.f;
#pragma unroll
      for (int k4 = 0; k4 < HID1 / 4; ++k4) {
        const float4 hv = *(const float4*)&h1s[n * H1_S + k4 * 4];
        acc += hv.x * w2r[k4 * 4 + 0] + hv.y * w2r[k4 * 4 + 1]
             + hv.z * w2r[k4 * 4 + 2] + hv.w * w2r[k4 * 4 + 3];
      }
      x2c[n] = acc;
    }
  }
  PHASE_FENCE();

  // ---- P3b: logits2 — head w (28 lanes/wave) ----
  if (lane < 28) {
    const int n = lane >> 1, sd = lane & 1;
    const float* uu = uvec + (sd ? U_UD2 : U_US2) + w * HID1;
    float s = 0.f;
#pragma unroll
    for (int k4 = 0; k4 < 8; ++k4) {
      const float4 hv = *(const float4*)&h1s[n * H1_S + k4 * 4];
      const float4 uv = *(const float4*)&uu[k4 * 4];
      s += hv.x * uv.x + hv.y * uv.y + hv.z * uv.z + hv.w * uv.w;
    }
    (sd ? ald2 : als2)[w][n] = s;
  }
  // ---- P3c: softmax2 — head w (14 lanes/wave) ----
  if (lane < NODES) {
    const float ad = ald2[w][lane];
    const float4 A0 = *(const float4*)&als2[w][0];
    const float4 A1 = *(const float4*)&als2[w][4];
    const float4 A2 = *(const float4*)&als2[w][8];
    const float2 A3 = *(const float2*)&als2[w][12];
    float a[NODES] = {A0.x, A0.y, A0.z, A0.w, A1.x, A1.y, A1.z, A1.w,
                      A2.x, A2.y, A2.z, A2.w, A3.x, A3.y};
    float m = -1e30f;
#pragma unroll
    for (int i = 0; i < NODES; ++i) {
      float v = a[i] + ad;
      v = v > 0.f ? v : SLOPE * v;
      a[i] = v; m = fmaxf(m, v);
    }
    float den = 0.f;
#pragma unroll
    for (int i = 0; i < NODES; ++i) { a[i] = __expf(a[i] - m); den += a[i]; }
    const float r = 1.f / den;
    float* wr = &wt2[w][lane * 16];
    *(float4*)&wr[0]  = make_float4(a[0]*r,  a[1]*r,  a[2]*r,  a[3]*r);
    *(float4*)&wr[4]  = make_float4(a[4]*r,  a[5]*r,  a[6]*r,  a[7]*r);
    *(float4*)&wr[8]  = make_float4(a[8]*r,  a[9]*r,  a[10]*r, a[11]*r);
    *(float2*)&wr[12] = make_float2(a[12]*r, a[13]*r);
  }
  // ---- P3d: agg2 — head w, all 14 targets per lane; bias pre-folded ----
  {
    const float bb = b2[lane];
#pragma unroll 2
    for (int n = 0; n < NODES; ++n) {
      const float* wr = &wt2[w][n * 16];
      const float4 w0 = *(const float4*)&wr[0];
      const float4 w1 = *(const float4*)&wr[4];
      const float4 w2 = *(const float4*)&wr[8];
      const float2 w3 = *(const float2*)&wr[12];
      const float o = w0.x*x2c[0] + w0.y*x2c[1] + w0.z*x2c[2] + w0.w*x2c[3]
                    + w1.x*x2c[4] + w1.y*x2c[5] + w1.z*x2c[6] + w1.w*x2c[7]
                    + w2.x*x2c[8] + w2.y*x2c[9] + w2.z*x2c[10] + w2.w*x2c[11]
                    + w3.x*x2c[12] + w3.y*x2c[13];
      h2p[w][n * H2_S + lane] = o + bb;
    }
  }
  __syncthreads();              // B3: h2p ready
  PHASE_FENCE();

  // ---- P4: MLP1 (112 lanes; h2 mean folded into the read) ----
  if (tid < NODES * 8) {
    const int k = tid >> 3, e = tid & 7;
    float acc = bf1[k * 8 + e];
#pragma unroll
    for (int f4 = 0; f4 < 16; ++f4) {
      const float4 A = *(const float4*)&h2p[0][k * H2_S + f4 * 4];
      const float4 B = *(const float4*)&h2p[1][k * H2_S + f4 * 4];
      acc += (0.5f * (A.x + B.x)) * Wf1[(k * HID2 + f4 * 4 + 0) * 8 + e]
           + (0.5f * (A.y + B.y)) * Wf1[(k * HID2 + f4 * 4 + 1) * 8 + e]
           + (0.5f * (A.z + B.z)) * Wf1[(k * HID2 + f4 * 4 + 2) * 8 + e]
           + (0.5f * (A.w + B.w)) * Wf1[(k * HID2 + f4 * 4 + 3) * 8 + e];
    }
    hhs[tid] = fmaxf(acc, 0.f);
  }
  __syncthreads();              // B4: hhs ready
  PHASE_FENCE();

  // ---- P5: MLP2 (336 outputs; float4 hhs reads) ----
  for (int idx = tid; idx < NODES * OUT_F; idx += 128) {
    const int k = idx / OUT_F, o = idx - k * OUT_F;
    const float4 h0 = *(const float4*)&hhs[k * 8];
    const float4 h1 = *(const float4*)&hhs[k * 8 + 4];
    float acc = bf2[k * OUT_F + o]
              + h0.x * Wf2[(k * 8 + 0) * OUT_F + o]
              + h0.y * Wf2[(k * 8 + 1) * OUT_F + o]
              + h0.z * Wf2[(k * 8 + 2) * OUT_F + o]
              + h0.w * Wf2[(k * 8 + 3) * OUT_F + o]
              + h1.x * Wf2[(k * 8 + 4) * OUT_F + o]
              + h1.y * Wf2[(k * 8 + 5) * OUT_F + o]
              + h1.z * Wf2[(k * 8 + 6) * OUT_F + o]
              + h1.w * Wf2[(k * 8 + 7) * OUT_F + o];
    out[(size_t)k * ngraphs * OUT_F + (size_t)g * OUT_F + o] =
        1.f / (1.f + __expf(-acc));
  }
}

extern "C" void kernel_launch(void* const* d_in, const int* in_sizes, int n_in,
                              void* d_out, int out_size, void* d_ws, size_t ws_size,
                              hipStream_t stream) {
  const float* x      = (const float*)d_in[0];
  const float* y      = (const float*)d_in[1];
  // d_in[2] = edge_index, d_in[3] = batch : structure fixed, unused
  const float* W1     = (const float*)d_in[4];
  const float* a_src1 = (const float*)d_in[5];
  const float* a_dst1 = (const float*)d_in[6];
  const float* b1     = (const float*)d_in[7];
  const float* W2     = (const float*)d_in[8];
  const float* a_src2 = (const float*)d_in[9];
  const float* a_dst2 = (const float*)d_in[10];
  const float* b2     = (const float*)d_in[11];
  const float* Wf1    = (const float*)d_in[12];
  const float* bf1    = (const float*)d_in[13];
  const float* Wf2    = (const float*)d_in[14];
  const float* bf2    = (const float*)d_in[15];
  float* out = (float*)d_out;
  float* u   = (float*)d_ws;

  const int nnodes  = in_sizes[0] / IN_F;
  const int ngraphs = nnodes / NODES;

  hipLaunchKernelGGL(compute_uvecs, dim3(1), dim3(256), 0, stream,
                     W1, a_src1, a_dst1, W2, a_src2, a_dst2, u);
  hipLaunchKernelGGL(gnn_fused, dim3(ngraphs), dim3(128), 0, stream,
                     x, y, W1, b1, W2, b2, Wf1, bf1, Wf2, bf2, u, out, ngraphs);
}